// Round 9
// baseline (905.891 us; speedup 1.0000x reference)
//
#include <hip/hip_runtime.h>
#include <hip/hip_fp16.h>

#define RES 256
#define FEAT 32
#define PLANE_ELEMS (FEAT * RES * RES)   // 2097152, fp16 plane = 4 MB
#define PLANE_BYTES (PLANE_ELEMS * 2)    // 4194304
#define NBINS 32768                      // 32^3 Morton bins
#define TQ_BLOCKS (3 * 256 * 4)          // transpose sub-grid of merged pre kernel

typedef unsigned u32x4 __attribute__((ext_vector_type(4)));

// ---------------- preprocessing ----------------

__device__ inline unsigned spread3(unsigned v) {
    unsigned r = 0;
    r |= (v & 1u);
    r |= (v & 2u) << 2;
    r |= (v & 4u) << 4;
    r |= (v & 8u) << 6;
    r |= (v & 16u) << 8;
    return r;
}

// Merged kernel A: blocks [0,TQ_BLOCKS) transpose+quantize planes (C,H,W)fp32 ->
// (H,W,C)fp16 via LDS tile; blocks [TQ_BLOCKS,..) build the Morton histogram.
// TAIL: the LAST block to finish (fence+ticket, no spinning -> no dispatch-order
// assumption, G16-safe) scans the 32768-bin hist in place (exclusive prefix).
// This removes the separate scan_hist dispatch (~25 us of launch overhead,
// measured across rounds 6/7/8: gap scales ~20-30 us per dispatch).
// Round-7 lesson: grid.sync() costs ~100 us/sync on 8 non-coherent XCDs — the
// ticket pattern has NO waiting; non-last blocks simply exit.
__global__ __launch_bounds__(256) void pre_tq_hist_scan(const float* __restrict__ p0,
                                                        const float* __restrict__ p1,
                                                        const float* __restrict__ p2,
                                                        __half* __restrict__ outp,
                                                        const float* __restrict__ pts,
                                                        const float* __restrict__ aabb,
                                                        int* __restrict__ hist,
                                                        int* __restrict__ done, int n) {
    __shared__ unsigned lds[64 * 17];            // transpose tile, pad 17
    __shared__ int sums[256];
    __shared__ int lastflag;
    int tid = threadIdx.x;

    if (blockIdx.x < TQ_BLOCKS) {
        int bid = blockIdx.x;
        int pl = bid >> 10;                      // /1024
        int rem = bid & 1023;
        int y = rem >> 2;
        int xbase = (rem & 3) * 64;
        const float* in = pl == 0 ? p0 : (pl == 1 ? p1 : p2);

        // phase 1: read along x (coalesced 256 B rows), pack channel pairs
        {
            int x = tid & 63;
            int c2b = (tid >> 6) * 4;            // 4 channel-pairs per thread
#pragma unroll
            for (int cc = 0; cc < 4; ++cc) {
                int c2 = c2b + cc;
                float f0 = in[(2 * c2) * (RES * RES) + y * RES + xbase + x];
                float f1 = in[(2 * c2 + 1) * (RES * RES) + y * RES + xbase + x];
                unsigned u = (unsigned)__half_as_ushort(__float2half(f0)) |
                             ((unsigned)__half_as_ushort(__float2half(f1)) << 16);
                lds[x * 17 + c2] = u;
            }
        }
        __syncthreads();
        // phase 2: write contiguous (x,c) order
        {
            unsigned* o32 = reinterpret_cast<unsigned*>(outp) + (size_t)pl * (PLANE_ELEMS / 2);
            int c2 = tid & 15;
            int xo = (tid >> 4) & 15;
#pragma unroll
            for (int xx = 0; xx < 4; ++xx) {
                int x = xx * 16 + xo;
                o32[(size_t)(y * 256 + xbase + x) * 16 + c2] = lds[x * 17 + c2];
            }
        }
    } else {
        int i = (blockIdx.x - TQ_BLOCKS) * 256 + tid;
        if (i < n) {
            float a00 = aabb[0], a01 = aabb[1], a02 = aabb[2];
            float a10 = aabb[3], a11 = aabb[4], a12 = aabb[5];
            float px = (pts[i * 3 + 0] - a00) * (2.0f / (a10 - a00)) - 1.0f;
            float py = (pts[i * 3 + 1] - a01) * (2.0f / (a11 - a01)) - 1.0f;
            float pz = (pts[i * 3 + 2] - a02) * (2.0f / (a12 - a02)) - 1.0f;
            unsigned ux = (unsigned)min(max((int)((px + 1.0f) * 16.0f), 0), 31);
            unsigned uy = (unsigned)min(max((int)((py + 1.0f) * 16.0f), 0), 31);
            unsigned uz = (unsigned)min(max((int)((pz + 1.0f) * 16.0f), 0), 31);
            int key = (int)(spread3(ux) | (spread3(uy) << 1) | (spread3(uz) << 2));
            atomicAdd(&hist[key], 1);
        }
    }

    // ---- common tail: fence + ticket; last block scans the histogram ----
    __syncthreads();
    __threadfence();                             // release our hist atomics / writes
    if (tid == 0) lastflag = (atomicAdd(done, 1) == (int)gridDim.x - 1) ? 1 : 0;
    __syncthreads();
    if (!lastflag) return;
    __threadfence();                             // acquire side

    int base = tid * 128;                        // 128 bins per thread
    int s = 0;
    for (int j = 0; j < 128; ++j)
        s += __hip_atomic_load(&hist[base + j], __ATOMIC_RELAXED, __HIP_MEMORY_SCOPE_AGENT);
    sums[tid] = s;
    __syncthreads();
    for (int off = 1; off < 256; off <<= 1) {
        int v = (tid >= off) ? sums[tid - off] : 0;
        __syncthreads();
        if (tid >= off) sums[tid] += v;
        __syncthreads();
    }
    int excl = (tid == 0) ? 0 : sums[tid - 1];
    for (int j = 0; j < 128; ++j) {
        int c = __hip_atomic_load(&hist[base + j], __ATOMIC_RELAXED, __HIP_MEMORY_SCOPE_AGENT);
        __hip_atomic_store(&hist[base + j], excl, __ATOMIC_RELAXED, __HIP_MEMORY_SCOPE_AGENT);
        excl += c;
    }
}

// Scatter sorted, pre-transformed records: [cx,cy,cz,0, hx,hy,hz,0] in pixel units.
// cx = (pxn+1)*127.5 ; hx = sx*63.75. Key recomputed from pts (identical float
// math to kernel A -> identical key; drops the 4 MB keys[] round-trip).
__global__ __launch_bounds__(256) void scatter_pack(const float* __restrict__ pts,
                                                    const float* __restrict__ scales,
                                                    const float* __restrict__ aabb,
                                                    int* __restrict__ hist,
                                                    float* __restrict__ ppk,
                                                    int* __restrict__ idx_s, int n) {
    int i = blockIdx.x * 256 + threadIdx.x;
    if (i >= n) return;
    float a00 = aabb[0], a01 = aabb[1], a02 = aabb[2];
    float a10 = aabb[3], a11 = aabb[4], a12 = aabb[5];
    float px = (pts[i * 3 + 0] - a00) * (2.0f / (a10 - a00)) - 1.0f;
    float py = (pts[i * 3 + 1] - a01) * (2.0f / (a11 - a01)) - 1.0f;
    float pz = (pts[i * 3 + 2] - a02) * (2.0f / (a12 - a02)) - 1.0f;
    unsigned ux = (unsigned)min(max((int)((px + 1.0f) * 16.0f), 0), 31);
    unsigned uy = (unsigned)min(max((int)((py + 1.0f) * 16.0f), 0), 31);
    unsigned uz = (unsigned)min(max((int)((pz + 1.0f) * 16.0f), 0), 31);
    int key = (int)(spread3(ux) | (spread3(uy) << 1) | (spread3(uz) << 2));
    int pos = atomicAdd(&hist[key], 1);
    float4* o = reinterpret_cast<float4*>(ppk) + (size_t)pos * 2;
    o[0] = make_float4((px + 1.0f) * 127.5f, (py + 1.0f) * 127.5f, (pz + 1.0f) * 127.5f, 0.0f);
    o[1] = make_float4(scales[i * 3 + 0] * 63.75f, scales[i * 3 + 1] * 63.75f,
                       scales[i * 3 + 2] * 63.75f, 0.0f);
    idx_s[pos] = i;
}

// ---------------- main kernel (round-6 validated, byte-identical) ----------------

// Guaranteed convert+FMA fusion: acc(f32) += f16(lo/hi of dword) * w(f32).
#define MIX2(f0, f1, d, w)                                                              \
    asm("v_fma_mix_f32 %0, %1, %2, %0 op_sel_hi:[1,0,0]" : "+v"(f0) : "v"(d), "v"(w)); \
    asm("v_fma_mix_f32 %0, %1, %2, %0 op_sel:[1,0,0] op_sel_hi:[1,0,0]" : "+v"(f1) : "v"(d), "v"(w))

__device__ __forceinline__ void mix8(float* fs, u32x4 v, float w) {
    MIX2(fs[0], fs[1], v[0], w);
    MIX2(fs[2], fs[3], v[1], w);
    MIX2(fs[4], fs[5], v[2], w);
    MIX2(fs[6], fs[7], v[3], w);
}

// 4 lanes per point, 8 channels per lane. One corner texel (64 B) = ONE wave load.
// Flat 39-sample pipeline across all 3 planes; buffers X/Y/Z rotate mod 3;
// steady state ISSUE(s+2); vmcnt(8); CONSUME(s); no inter-plane drains.
// (Validated round 6: 172 us, VGPR 88, FETCH 28 MB. Sorted input REQUIRED:
// round 8 measured unsorted = 1.18 GB fetch, 365 us.)
__global__ __launch_bounds__(256) void wpf_main4(const float* __restrict__ ppk,
                                                 const int* __restrict__ idx_s,
                                                 const __half* __restrict__ planes, // 3 concat
                                                 float* __restrict__ out, int n, int swizzle) {
    int b = blockIdx.x;
    if (swizzle) {
        int nb = gridDim.x;
        int chunk = nb >> 3;
        b = (b & 7) * chunk + (b >> 3);
    }
    int t = b * 256 + threadIdx.x;
    int pt = t >> 2;
    int cg_ = t & 3;
    if (pt >= n) return;

    float4 a  = reinterpret_cast<const float4*>(ppk)[(size_t)pt * 2];
    float4 hh = reinterpret_cast<const float4*>(ppk)[(size_t)pt * 2 + 1];
    int chan = cg_ * 16;                 // byte offset of this lane's 8 channels

    const int SI[13] = {2, 0, 1, 3, 4, 2, 2, 2, 2, 3, 3, 1, 1};
    const int SJ[13] = {2, 2, 2, 2, 2, 0, 1, 3, 4, 3, 1, 3, 1};

    float wx[2][5], wy[2][5];
    int   cA[2][5], rA[2][5];
    float fs[8] = {0, 0, 0, 0, 0, 0, 0, 0};
    float interp[8];
    u32x4 X0, X1, X2, X3, Y0, Y1, Y2, Y3, Z0, Z1, Z2, Z3;

#define SETUP(SET, CX, CY, HX, HY, POFF)                 \
    _Pragma("unroll")                                    \
    for (int k = 0; k < 5; ++k) {                        \
        float x_ = fmaf((float)(k - 2), (HX), (CX));     \
        int xi_ = (int)x_;              /* trunc==floor, x>0 */ \
        wx[SET][k] = x_ - (float)xi_;                    \
        cA[SET][k] = xi_ * 64 + chan;                    \
        float y_ = fmaf((float)(k - 2), (HY), (CY));     \
        int yi_ = (int)y_;                               \
        wy[SET][k] = y_ - (float)yi_;                    \
        rA[SET][k] = yi_ * (RES * 64) + (POFF);          \
    }

#define ISSUE(d0, d1, d2, d3, SET, M)                                                     \
    {                                                                                     \
        unsigned vo0_ = (unsigned)(rA[SET][SJ[M]] + cA[SET][SI[M]]);                      \
        unsigned vo1_ = vo0_ + 16384u;                                                    \
        asm volatile("global_load_dwordx4 %0, %1, %2"           : "=v"(d0) : "v"(vo0_), "s"(planes)); \
        asm volatile("global_load_dwordx4 %0, %1, %2 offset:64" : "=v"(d1) : "v"(vo0_), "s"(planes)); \
        asm volatile("global_load_dwordx4 %0, %1, %2"           : "=v"(d2) : "v"(vo1_), "s"(planes)); \
        asm volatile("global_load_dwordx4 %0, %1, %2 offset:64" : "=v"(d3) : "v"(vo1_), "s"(planes)); \
    }
#define WAIT8(b0, b1, b2, b3) \
    asm volatile("s_waitcnt vmcnt(8)" : "+v"(b0), "+v"(b1), "+v"(b2), "+v"(b3))
#define WAIT4(b0, b1, b2, b3) \
    asm volatile("s_waitcnt vmcnt(4)" : "+v"(b0), "+v"(b1), "+v"(b2), "+v"(b3))
#define WAITZ(b0, b1, b2, b3) \
    asm volatile("s_waitcnt vmcnt(0)" : "+v"(b0), "+v"(b1), "+v"(b2), "+v"(b3))
#define CONSUME(SET, M, b0, b1, b2, b3)                  \
    {                                                    \
        float wxi = wx[SET][SI[M]], wyj = wy[SET][SJ[M]];\
        float wxc = 1.0f - wxi, wyc = 1.0f - wyj;        \
        mix8(fs, b0, wxc * wyc);                         \
        mix8(fs, b1, wxi * wyc);                         \
        mix8(fs, b2, wxc * wyj);                         \
        mix8(fs, b3, wxi * wyj);                         \
    }
#define STEP(CS, CSET, ISET, C0, C1, C2, C3, N0, N1, N2, N3) \
    ISSUE(N0, N1, N2, N3, ISET, ((CS) + 2) % 13);            \
    WAIT8(C0, C1, C2, C3);                                   \
    CONSUME(CSET, (CS) % 13, C0, C1, C2, C3);

        SETUP(0, a.x, a.y, hh.x, hh.y, 0)                 // plane 0
        ISSUE(X0, X1, X2, X3, 0, 0);
        ISSUE(Y0, Y1, Y2, Y3, 0, 1);
        STEP(0,  0, 0, X0, X1, X2, X3, Z0, Z1, Z2, Z3)
        STEP(1,  0, 0, Y0, Y1, Y2, Y3, X0, X1, X2, X3)
        STEP(2,  0, 0, Z0, Z1, Z2, Z3, Y0, Y1, Y2, Y3)
        STEP(3,  0, 0, X0, X1, X2, X3, Z0, Z1, Z2, Z3)
        STEP(4,  0, 0, Y0, Y1, Y2, Y3, X0, X1, X2, X3)
        STEP(5,  0, 0, Z0, Z1, Z2, Z3, Y0, Y1, Y2, Y3)
        STEP(6,  0, 0, X0, X1, X2, X3, Z0, Z1, Z2, Z3)
        STEP(7,  0, 0, Y0, Y1, Y2, Y3, X0, X1, X2, X3)
        STEP(8,  0, 0, Z0, Z1, Z2, Z3, Y0, Y1, Y2, Y3)
        STEP(9,  0, 0, X0, X1, X2, X3, Z0, Z1, Z2, Z3)
        STEP(10, 0, 0, Y0, Y1, Y2, Y3, X0, X1, X2, X3)
        SETUP(1, a.x, a.z, hh.x, hh.z, PLANE_BYTES)       // plane 1 slots, early
        STEP(11, 0, 1, Z0, Z1, Z2, Z3, Y0, Y1, Y2, Y3)    // issues s13 = p1 m0
        STEP(12, 0, 1, X0, X1, X2, X3, Z0, Z1, Z2, Z3)    // consumes p0 m12
#pragma unroll
        for (int c = 0; c < 8; ++c) { interp[c] = fs[c]; fs[c] = 0.0f; }
        STEP(13, 1, 1, Y0, Y1, Y2, Y3, X0, X1, X2, X3)
        STEP(14, 1, 1, Z0, Z1, Z2, Z3, Y0, Y1, Y2, Y3)
        STEP(15, 1, 1, X0, X1, X2, X3, Z0, Z1, Z2, Z3)
        STEP(16, 1, 1, Y0, Y1, Y2, Y3, X0, X1, X2, X3)
        STEP(17, 1, 1, Z0, Z1, Z2, Z3, Y0, Y1, Y2, Y3)
        STEP(18, 1, 1, X0, X1, X2, X3, Z0, Z1, Z2, Z3)
        STEP(19, 1, 1, Y0, Y1, Y2, Y3, X0, X1, X2, X3)
        STEP(20, 1, 1, Z0, Z1, Z2, Z3, Y0, Y1, Y2, Y3)
        STEP(21, 1, 1, X0, X1, X2, X3, Z0, Z1, Z2, Z3)
        STEP(22, 1, 1, Y0, Y1, Y2, Y3, X0, X1, X2, X3)
        STEP(23, 1, 1, Z0, Z1, Z2, Z3, Y0, Y1, Y2, Y3)
        SETUP(0, a.y, a.z, hh.y, hh.z, 2 * PLANE_BYTES)   // plane 2 slots, early
        STEP(24, 1, 0, X0, X1, X2, X3, Z0, Z1, Z2, Z3)    // issues s26 = p2 m0
        STEP(25, 1, 0, Y0, Y1, Y2, Y3, X0, X1, X2, X3)    // consumes p1 m12
#pragma unroll
        for (int c = 0; c < 8; ++c) { interp[c] *= fs[c]; fs[c] = 0.0f; }
        STEP(26, 0, 0, Z0, Z1, Z2, Z3, Y0, Y1, Y2, Y3)
        STEP(27, 0, 0, X0, X1, X2, X3, Z0, Z1, Z2, Z3)
        STEP(28, 0, 0, Y0, Y1, Y2, Y3, X0, X1, X2, X3)
        STEP(29, 0, 0, Z0, Z1, Z2, Z3, Y0, Y1, Y2, Y3)
        STEP(30, 0, 0, X0, X1, X2, X3, Z0, Z1, Z2, Z3)
        STEP(31, 0, 0, Y0, Y1, Y2, Y3, X0, X1, X2, X3)
        STEP(32, 0, 0, Z0, Z1, Z2, Z3, Y0, Y1, Y2, Y3)
        STEP(33, 0, 0, X0, X1, X2, X3, Z0, Z1, Z2, Z3)
        STEP(34, 0, 0, Y0, Y1, Y2, Y3, X0, X1, X2, X3)
        STEP(35, 0, 0, Z0, Z1, Z2, Z3, Y0, Y1, Y2, Y3)
        STEP(36, 0, 0, X0, X1, X2, X3, Z0, Z1, Z2, Z3)    // issues s38 = p2 m12
        WAIT4(Y0, Y1, Y2, Y3);                            // s37 ready, s38 in flight
        CONSUME(0, 11, Y0, Y1, Y2, Y3);
        WAITZ(Z0, Z1, Z2, Z3);                            // s38 ready
        CONSUME(0, 12, Z0, Z1, Z2, Z3);

#undef SETUP
#undef ISSUE
#undef WAIT8
#undef WAIT4
#undef WAITZ
#undef CONSUME
#undef STEP

    const float inv = 1.0f / 2197.0f;    // (1/13)^3 folded into epilogue
    int oi = idx_s[pt];
    float4* o = reinterpret_cast<float4*>(out + (size_t)oi * 32 + cg_ * 8);
    o[0] = make_float4(interp[0] * fs[0] * inv, interp[1] * fs[1] * inv,
                       interp[2] * fs[2] * inv, interp[3] * fs[3] * inv);
    o[1] = make_float4(interp[4] * fs[4] * inv, interp[5] * fs[5] * inv,
                       interp[6] * fs[6] * inv, interp[7] * fs[7] * inv);
}

// ---------------- fallback (ws too small): direct fp32 strided path ----------------
__global__ __launch_bounds__(256) void wpf_plain(const float* __restrict__ pts,
                                                 const float* __restrict__ scales,
                                                 const float* __restrict__ p0,
                                                 const float* __restrict__ p1,
                                                 const float* __restrict__ p2,
                                                 const float* __restrict__ aabb,
                                                 float* __restrict__ out, int n) {
    const float offx[13] = {0.f, -1.f, -0.5f, 0.5f, 1.f, 0.f, 0.f, 0.f, 0.f, 0.5f, 0.5f, -0.5f, -0.5f};
    const float offy[13] = {0.f, 0.f, 0.f, 0.f, 0.f, -1.f, -0.5f, 0.5f, 1.f, 0.5f, -0.5f, 0.5f, -0.5f};
    int t = blockIdx.x * 256 + threadIdx.x;
    int pt = t >> 3;
    int cg_ = t & 7;
    if (pt >= n) return;
    float a00 = aabb[0], a01 = aabb[1], a02 = aabb[2];
    float a10 = aabb[3], a11 = aabb[4], a12 = aabb[5];
    float px = (pts[pt * 3 + 0] - a00) * (2.0f / (a10 - a00)) - 1.0f;
    float py = (pts[pt * 3 + 1] - a01) * (2.0f / (a11 - a01)) - 1.0f;
    float pz = (pts[pt * 3 + 2] - a02) * (2.0f / (a12 - a02)) - 1.0f;
    float scx = scales[pt * 3 + 0], scy = scales[pt * 3 + 1], scz = scales[pt * 3 + 2];
    float4 interp = make_float4(1.f, 1.f, 1.f, 1.f);
    for (int pair = 0; pair < 3; ++pair) {
        const float* plane = pair == 0 ? p0 : (pair == 1 ? p1 : p2);
        float bx = pair == 2 ? py : px;
        float by = pair == 0 ? py : pz;
        float sx = pair == 2 ? scy : scx;
        float sy = pair == 0 ? scy : scz;
        float4 featsum = make_float4(0.f, 0.f, 0.f, 0.f);
        for (int s = 0; s < 13; ++s) {
            float x = fminf(fmaxf((bx + sx * offx[s] + 1.0f) * 127.5f, 0.0f), 255.0f);
            float y = fminf(fmaxf((by + sy * offy[s] + 1.0f) * 127.5f, 0.0f), 255.0f);
            float x0f = floorf(x), y0f = floorf(y);
            float wx = x - x0f, wy = y - y0f;
            int x0 = (int)x0f, y0 = (int)y0f;
            int x1 = min(x0 + 1, RES - 1), y1 = min(y0 + 1, RES - 1);
            float w00 = (1.0f - wx) * (1.0f - wy), w10 = wx * (1.0f - wy);
            float w01 = (1.0f - wx) * wy, w11 = wx * wy;
            int c0 = cg_ << 2;
            for (int c = 0; c < 4; ++c) {
                const float* pl = plane + (size_t)(c0 + c) * (RES * RES);
                float f = pl[y0 * RES + x0] * w00 + pl[y0 * RES + x1] * w10 +
                          pl[y1 * RES + x0] * w01 + pl[y1 * RES + x1] * w11;
                (&featsum.x)[c] += f;
            }
        }
        const float inv13 = 1.0f / 13.0f;
        interp.x *= featsum.x * inv13;
        interp.y *= featsum.y * inv13;
        interp.z *= featsum.z * inv13;
        interp.w *= featsum.w * inv13;
    }
    reinterpret_cast<float4*>(out)[(size_t)pt * 8 + cg_] = interp;
}

extern "C" void kernel_launch(void* const* d_in, const int* in_sizes, int n_in,
                              void* d_out, int out_size, void* d_ws, size_t ws_size,
                              hipStream_t stream) {
    const float* pts    = (const float*)d_in[0];
    const float* scales = (const float*)d_in[2];
    const float* p0     = (const float*)d_in[3];
    const float* p1     = (const float*)d_in[4];
    const float* p2     = (const float*)d_in[5];
    const float* aabb   = (const float*)d_in[6];
    float* out = (float*)d_out;

    int n = in_sizes[0] / 3;
    int pt_blocks = (n + 255) / 256;

    // workspace layout
    size_t planes_hbytes = (size_t)3 * PLANE_ELEMS * sizeof(__half);  // 12 MB
    size_t ppk_bytes = (size_t)n * 8 * sizeof(float);                 // 16 MB
    size_t idx_bytes = (size_t)n * sizeof(int);                       // 2 MB
    size_t hist_bytes = (size_t)(NBINS + 1) * sizeof(int);            // hist + done
    size_t need = planes_hbytes + ppk_bytes + idx_bytes + hist_bytes;

    if (ws_size >= need) {
        __half* planes_h = (__half*)d_ws;
        float*  ppk   = (float*)((char*)d_ws + planes_hbytes);
        int*    idx_s = (int*)((char*)ppk + ppk_bytes);
        int*    hist  = idx_s + n;
        int*    done  = hist + NBINS;

        hipMemsetAsync(hist, 0, hist_bytes, stream);
        pre_tq_hist_scan<<<TQ_BLOCKS + pt_blocks, 256, 0, stream>>>(p0, p1, p2, planes_h,
                                                                    pts, aabb, hist, done, n);
        scatter_pack<<<pt_blocks, 256, 0, stream>>>(pts, scales, aabb, hist,
                                                    ppk, idx_s, n);
        int main_blocks = (n * 4 + 255) / 256;
        int swizzle = (main_blocks % 8 == 0) ? 1 : 0;
        wpf_main4<<<main_blocks, 256, 0, stream>>>(ppk, idx_s, planes_h, out, n, swizzle);
    } else {
        int main_blocks = (n * 8 + 255) / 256;
        wpf_plain<<<main_blocks, 256, 0, stream>>>(pts, scales, p0, p1, p2, aabb, out, n);
    }
}

// Round 10
// 322.499 us; speedup vs baseline: 2.8090x; 2.8090x over previous
//
#include <hip/hip_runtime.h>
#include <hip/hip_fp16.h>

#define RES 256
#define FEAT 32
#define PLANE_ELEMS (FEAT * RES * RES)   // 2097152, fp16 plane = 4 MB
#define PLANE_BYTES (PLANE_ELEMS * 2)    // 4194304
#define NBINS 32768                      // 32^3 Morton bins
#define TQ_BLOCKS (3 * 256 * 4)          // transpose sub-grid of merged pre kernel

typedef unsigned u32x4 __attribute__((ext_vector_type(4)));

// ---------------- preprocessing ----------------
// LEDGER (do not retry): grid.sync() ~100us/sync (r7, VALUBusy 0.8%); per-block
// device __threadfence ticket ~600us (r9, VALUBusy 0.4%) — cross-XCD visibility
// ops at grid scale are catastrophically expensive on 8 non-coherent L2s.
// Dispatch boundaries (~20-30us each) are the CHEAP ordering primitive here.
// Sort removal: main 172->365us, FETCH 28MB->1.18GB (r8). Sort is mandatory.

__device__ inline unsigned spread3(unsigned v) {
    unsigned r = 0;
    r |= (v & 1u);
    r |= (v & 2u) << 2;
    r |= (v & 4u) << 4;
    r |= (v & 8u) << 6;
    r |= (v & 16u) << 8;
    return r;
}

// Merged: blocks [0,TQ_BLOCKS) transpose+quantize planes (C,H,W)fp32 -> (H,W,C)fp16
// via LDS tile; blocks [TQ_BLOCKS, ...) build Morton histogram (keys NOT stored;
// scatter recomputes them from pts with identical float math).
__global__ __launch_bounds__(256) void pre_tq_hist(const float* __restrict__ p0,
                                                   const float* __restrict__ p1,
                                                   const float* __restrict__ p2,
                                                   __half* __restrict__ outp,
                                                   const float* __restrict__ pts,
                                                   const float* __restrict__ aabb,
                                                   int* __restrict__ hist, int n) {
    int tid = threadIdx.x;
    if (blockIdx.x < TQ_BLOCKS) {
        __shared__ unsigned lds[64 * 17];            // [x][c2], pad 17: conflict-free
        int bid = blockIdx.x;
        int pl = bid >> 10;                          // /1024
        int rem = bid & 1023;
        int y = rem >> 2;
        int xbase = (rem & 3) * 64;
        const float* in = pl == 0 ? p0 : (pl == 1 ? p1 : p2);

        // phase 1: read along x (coalesced 256 B rows), pack channel pairs
        {
            int x = tid & 63;
            int c2b = (tid >> 6) * 4;                // 4 channel-pairs per thread
#pragma unroll
            for (int cc = 0; cc < 4; ++cc) {
                int c2 = c2b + cc;
                float f0 = in[(2 * c2) * (RES * RES) + y * RES + xbase + x];
                float f1 = in[(2 * c2 + 1) * (RES * RES) + y * RES + xbase + x];
                unsigned u = (unsigned)__half_as_ushort(__float2half(f0)) |
                             ((unsigned)__half_as_ushort(__float2half(f1)) << 16);
                lds[x * 17 + c2] = u;
            }
        }
        __syncthreads();

        // phase 2: write contiguous (x,c) order
        {
            unsigned* o32 = reinterpret_cast<unsigned*>(outp) + (size_t)pl * (PLANE_ELEMS / 2);
            int c2 = tid & 15;
            int xo = (tid >> 4) & 15;
#pragma unroll
            for (int xx = 0; xx < 4; ++xx) {
                int x = xx * 16 + xo;
                o32[(size_t)(y * 256 + xbase + x) * 16 + c2] = lds[x * 17 + c2];
            }
        }
    } else {
        int i = (blockIdx.x - TQ_BLOCKS) * 256 + tid;
        if (i >= n) return;
        float a00 = aabb[0], a01 = aabb[1], a02 = aabb[2];
        float a10 = aabb[3], a11 = aabb[4], a12 = aabb[5];
        float px = (pts[i * 3 + 0] - a00) * (2.0f / (a10 - a00)) - 1.0f;
        float py = (pts[i * 3 + 1] - a01) * (2.0f / (a11 - a01)) - 1.0f;
        float pz = (pts[i * 3 + 2] - a02) * (2.0f / (a12 - a02)) - 1.0f;
        unsigned ux = (unsigned)min(max((int)((px + 1.0f) * 16.0f), 0), 31);
        unsigned uy = (unsigned)min(max((int)((py + 1.0f) * 16.0f), 0), 31);
        unsigned uz = (unsigned)min(max((int)((pz + 1.0f) * 16.0f), 0), 31);
        int key = (int)(spread3(ux) | (spread3(uy) << 1) | (spread3(uz) << 2));
        atomicAdd(&hist[key], 1);
    }
}

__global__ __launch_bounds__(1024) void scan_hist(int* __restrict__ hist) {
    __shared__ int sums[1024];
    int t = threadIdx.x;
    int base = t * 32;
    int4 L[8];
    const int4* h4 = reinterpret_cast<const int4*>(hist + base);
#pragma unroll
    for (int i = 0; i < 8; ++i) L[i] = h4[i];
    int s = 0;
#pragma unroll
    for (int i = 0; i < 8; ++i) s += L[i].x + L[i].y + L[i].z + L[i].w;
    sums[t] = s;
    __syncthreads();
    for (int off = 1; off < 1024; off <<= 1) {
        int v = 0;
        if (t >= off) v = sums[t - off];
        __syncthreads();
        if (t >= off) sums[t] += v;
        __syncthreads();
    }
    int excl = (t == 0) ? 0 : sums[t - 1];
    int4* o4 = reinterpret_cast<int4*>(hist + base);
#pragma unroll
    for (int i = 0; i < 8; ++i) {
        int4 v;
        v.x = excl; excl += L[i].x;
        v.y = excl; excl += L[i].y;
        v.z = excl; excl += L[i].z;
        v.w = excl; excl += L[i].w;
        o4[i] = v;
    }
}

// Scatter sorted, pre-transformed records: [cx,cy,cz,0, hx,hy,hz,0] in pixel units.
// cx = (pxn+1)*127.5 ; hx = sx*63.75. Key recomputed from pts (identical float
// math to pre_tq_hist -> identical key; drops the 4 MB keys[] round-trip).
__global__ __launch_bounds__(256) void scatter_pack(const float* __restrict__ pts,
                                                    const float* __restrict__ scales,
                                                    const float* __restrict__ aabb,
                                                    int* __restrict__ hist,
                                                    float* __restrict__ ppk,
                                                    int* __restrict__ idx_s, int n) {
    int i = blockIdx.x * 256 + threadIdx.x;
    if (i >= n) return;
    float a00 = aabb[0], a01 = aabb[1], a02 = aabb[2];
    float a10 = aabb[3], a11 = aabb[4], a12 = aabb[5];
    float px = (pts[i * 3 + 0] - a00) * (2.0f / (a10 - a00)) - 1.0f;
    float py = (pts[i * 3 + 1] - a01) * (2.0f / (a11 - a01)) - 1.0f;
    float pz = (pts[i * 3 + 2] - a02) * (2.0f / (a12 - a02)) - 1.0f;
    unsigned ux = (unsigned)min(max((int)((px + 1.0f) * 16.0f), 0), 31);
    unsigned uy = (unsigned)min(max((int)((py + 1.0f) * 16.0f), 0), 31);
    unsigned uz = (unsigned)min(max((int)((pz + 1.0f) * 16.0f), 0), 31);
    int key = (int)(spread3(ux) | (spread3(uy) << 1) | (spread3(uz) << 2));
    int pos = atomicAdd(&hist[key], 1);
    float4* o = reinterpret_cast<float4*>(ppk) + (size_t)pos * 2;
    o[0] = make_float4((px + 1.0f) * 127.5f, (py + 1.0f) * 127.5f, (pz + 1.0f) * 127.5f, 0.0f);
    o[1] = make_float4(scales[i * 3 + 0] * 63.75f, scales[i * 3 + 1] * 63.75f,
                       scales[i * 3 + 2] * 63.75f, 0.0f);
    idx_s[pos] = i;
}

// ---------------- main kernel (round-6 validated, byte-identical) ----------------

// Guaranteed convert+FMA fusion: acc(f32) += f16(lo/hi of dword) * w(f32).
#define MIX2(f0, f1, d, w)                                                              \
    asm("v_fma_mix_f32 %0, %1, %2, %0 op_sel_hi:[1,0,0]" : "+v"(f0) : "v"(d), "v"(w)); \
    asm("v_fma_mix_f32 %0, %1, %2, %0 op_sel:[1,0,0] op_sel_hi:[1,0,0]" : "+v"(f1) : "v"(d), "v"(w))

__device__ __forceinline__ void mix8(float* fs, u32x4 v, float w) {
    MIX2(fs[0], fs[1], v[0], w);
    MIX2(fs[2], fs[3], v[1], w);
    MIX2(fs[4], fs[5], v[2], w);
    MIX2(fs[6], fs[7], v[3], w);
}

// 4 lanes per point, 8 channels per lane. One corner texel (64 B) = ONE wave load.
// Flat 39-sample pipeline across all 3 planes; buffers X/Y/Z rotate mod 3;
// steady state ISSUE(s+2); vmcnt(8); CONSUME(s); no inter-plane drains.
// (Validated round 6: 172 us, VGPR 88, FETCH 28 MB. Sorted input REQUIRED:
// round 8 measured unsorted = 1.18 GB fetch, 365 us.)
__global__ __launch_bounds__(256) void wpf_main4(const float* __restrict__ ppk,
                                                 const int* __restrict__ idx_s,
                                                 const __half* __restrict__ planes, // 3 concat
                                                 float* __restrict__ out, int n, int swizzle) {
    int b = blockIdx.x;
    if (swizzle) {
        int nb = gridDim.x;
        int chunk = nb >> 3;
        b = (b & 7) * chunk + (b >> 3);
    }
    int t = b * 256 + threadIdx.x;
    int pt = t >> 2;
    int cg_ = t & 3;
    if (pt >= n) return;

    float4 a  = reinterpret_cast<const float4*>(ppk)[(size_t)pt * 2];
    float4 hh = reinterpret_cast<const float4*>(ppk)[(size_t)pt * 2 + 1];
    int chan = cg_ * 16;                 // byte offset of this lane's 8 channels

    const int SI[13] = {2, 0, 1, 3, 4, 2, 2, 2, 2, 3, 3, 1, 1};
    const int SJ[13] = {2, 2, 2, 2, 2, 0, 1, 3, 4, 3, 1, 3, 1};

    float wx[2][5], wy[2][5];
    int   cA[2][5], rA[2][5];
    float fs[8] = {0, 0, 0, 0, 0, 0, 0, 0};
    float interp[8];
    u32x4 X0, X1, X2, X3, Y0, Y1, Y2, Y3, Z0, Z1, Z2, Z3;

#define SETUP(SET, CX, CY, HX, HY, POFF)                 \
    _Pragma("unroll")                                    \
    for (int k = 0; k < 5; ++k) {                        \
        float x_ = fmaf((float)(k - 2), (HX), (CX));     \
        int xi_ = (int)x_;              /* trunc==floor, x>0 */ \
        wx[SET][k] = x_ - (float)xi_;                    \
        cA[SET][k] = xi_ * 64 + chan;                    \
        float y_ = fmaf((float)(k - 2), (HY), (CY));     \
        int yi_ = (int)y_;                               \
        wy[SET][k] = y_ - (float)yi_;                    \
        rA[SET][k] = yi_ * (RES * 64) + (POFF);          \
    }

#define ISSUE(d0, d1, d2, d3, SET, M)                                                     \
    {                                                                                     \
        unsigned vo0_ = (unsigned)(rA[SET][SJ[M]] + cA[SET][SI[M]]);                      \
        unsigned vo1_ = vo0_ + 16384u;                                                    \
        asm volatile("global_load_dwordx4 %0, %1, %2"           : "=v"(d0) : "v"(vo0_), "s"(planes)); \
        asm volatile("global_load_dwordx4 %0, %1, %2 offset:64" : "=v"(d1) : "v"(vo0_), "s"(planes)); \
        asm volatile("global_load_dwordx4 %0, %1, %2"           : "=v"(d2) : "v"(vo1_), "s"(planes)); \
        asm volatile("global_load_dwordx4 %0, %1, %2 offset:64" : "=v"(d3) : "v"(vo1_), "s"(planes)); \
    }
#define WAIT8(b0, b1, b2, b3) \
    asm volatile("s_waitcnt vmcnt(8)" : "+v"(b0), "+v"(b1), "+v"(b2), "+v"(b3))
#define WAIT4(b0, b1, b2, b3) \
    asm volatile("s_waitcnt vmcnt(4)" : "+v"(b0), "+v"(b1), "+v"(b2), "+v"(b3))
#define WAITZ(b0, b1, b2, b3) \
    asm volatile("s_waitcnt vmcnt(0)" : "+v"(b0), "+v"(b1), "+v"(b2), "+v"(b3))
#define CONSUME(SET, M, b0, b1, b2, b3)                  \
    {                                                    \
        float wxi = wx[SET][SI[M]], wyj = wy[SET][SJ[M]];\
        float wxc = 1.0f - wxi, wyc = 1.0f - wyj;        \
        mix8(fs, b0, wxc * wyc);                         \
        mix8(fs, b1, wxi * wyc);                         \
        mix8(fs, b2, wxc * wyj);                         \
        mix8(fs, b3, wxi * wyj);                         \
    }
#define STEP(CS, CSET, ISET, C0, C1, C2, C3, N0, N1, N2, N3) \
    ISSUE(N0, N1, N2, N3, ISET, ((CS) + 2) % 13);            \
    WAIT8(C0, C1, C2, C3);                                   \
    CONSUME(CSET, (CS) % 13, C0, C1, C2, C3);

        SETUP(0, a.x, a.y, hh.x, hh.y, 0)                 // plane 0
        ISSUE(X0, X1, X2, X3, 0, 0);
        ISSUE(Y0, Y1, Y2, Y3, 0, 1);
        STEP(0,  0, 0, X0, X1, X2, X3, Z0, Z1, Z2, Z3)
        STEP(1,  0, 0, Y0, Y1, Y2, Y3, X0, X1, X2, X3)
        STEP(2,  0, 0, Z0, Z1, Z2, Z3, Y0, Y1, Y2, Y3)
        STEP(3,  0, 0, X0, X1, X2, X3, Z0, Z1, Z2, Z3)
        STEP(4,  0, 0, Y0, Y1, Y2, Y3, X0, X1, X2, X3)
        STEP(5,  0, 0, Z0, Z1, Z2, Z3, Y0, Y1, Y2, Y3)
        STEP(6,  0, 0, X0, X1, X2, X3, Z0, Z1, Z2, Z3)
        STEP(7,  0, 0, Y0, Y1, Y2, Y3, X0, X1, X2, X3)
        STEP(8,  0, 0, Z0, Z1, Z2, Z3, Y0, Y1, Y2, Y3)
        STEP(9,  0, 0, X0, X1, X2, X3, Z0, Z1, Z2, Z3)
        STEP(10, 0, 0, Y0, Y1, Y2, Y3, X0, X1, X2, X3)
        SETUP(1, a.x, a.z, hh.x, hh.z, PLANE_BYTES)       // plane 1 slots, early
        STEP(11, 0, 1, Z0, Z1, Z2, Z3, Y0, Y1, Y2, Y3)    // issues s13 = p1 m0
        STEP(12, 0, 1, X0, X1, X2, X3, Z0, Z1, Z2, Z3)    // consumes p0 m12
#pragma unroll
        for (int c = 0; c < 8; ++c) { interp[c] = fs[c]; fs[c] = 0.0f; }
        STEP(13, 1, 1, Y0, Y1, Y2, Y3, X0, X1, X2, X3)
        STEP(14, 1, 1, Z0, Z1, Z2, Z3, Y0, Y1, Y2, Y3)
        STEP(15, 1, 1, X0, X1, X2, X3, Z0, Z1, Z2, Z3)
        STEP(16, 1, 1, Y0, Y1, Y2, Y3, X0, X1, X2, X3)
        STEP(17, 1, 1, Z0, Z1, Z2, Z3, Y0, Y1, Y2, Y3)
        STEP(18, 1, 1, X0, X1, X2, X3, Z0, Z1, Z2, Z3)
        STEP(19, 1, 1, Y0, Y1, Y2, Y3, X0, X1, X2, X3)
        STEP(20, 1, 1, Z0, Z1, Z2, Z3, Y0, Y1, Y2, Y3)
        STEP(21, 1, 1, X0, X1, X2, X3, Z0, Z1, Z2, Z3)
        STEP(22, 1, 1, Y0, Y1, Y2, Y3, X0, X1, X2, X3)
        STEP(23, 1, 1, Z0, Z1, Z2, Z3, Y0, Y1, Y2, Y3)
        SETUP(0, a.y, a.z, hh.y, hh.z, 2 * PLANE_BYTES)   // plane 2 slots, early
        STEP(24, 1, 0, X0, X1, X2, X3, Z0, Z1, Z2, Z3)    // issues s26 = p2 m0
        STEP(25, 1, 0, Y0, Y1, Y2, Y3, X0, X1, X2, X3)    // consumes p1 m12
#pragma unroll
        for (int c = 0; c < 8; ++c) { interp[c] *= fs[c]; fs[c] = 0.0f; }
        STEP(26, 0, 0, Z0, Z1, Z2, Z3, Y0, Y1, Y2, Y3)
        STEP(27, 0, 0, X0, X1, X2, X3, Z0, Z1, Z2, Z3)
        STEP(28, 0, 0, Y0, Y1, Y2, Y3, X0, X1, X2, X3)
        STEP(29, 0, 0, Z0, Z1, Z2, Z3, Y0, Y1, Y2, Y3)
        STEP(30, 0, 0, X0, X1, X2, X3, Z0, Z1, Z2, Z3)
        STEP(31, 0, 0, Y0, Y1, Y2, Y3, X0, X1, X2, X3)
        STEP(32, 0, 0, Z0, Z1, Z2, Z3, Y0, Y1, Y2, Y3)
        STEP(33, 0, 0, X0, X1, X2, X3, Z0, Z1, Z2, Z3)
        STEP(34, 0, 0, Y0, Y1, Y2, Y3, X0, X1, X2, X3)
        STEP(35, 0, 0, Z0, Z1, Z2, Z3, Y0, Y1, Y2, Y3)
        STEP(36, 0, 0, X0, X1, X2, X3, Z0, Z1, Z2, Z3)    // issues s38 = p2 m12
        WAIT4(Y0, Y1, Y2, Y3);                            // s37 ready, s38 in flight
        CONSUME(0, 11, Y0, Y1, Y2, Y3);
        WAITZ(Z0, Z1, Z2, Z3);                            // s38 ready
        CONSUME(0, 12, Z0, Z1, Z2, Z3);

#undef SETUP
#undef ISSUE
#undef WAIT8
#undef WAIT4
#undef WAITZ
#undef CONSUME
#undef STEP

    const float inv = 1.0f / 2197.0f;    // (1/13)^3 folded into epilogue
    int oi = idx_s[pt];
    float4* o = reinterpret_cast<float4*>(out + (size_t)oi * 32 + cg_ * 8);
    o[0] = make_float4(interp[0] * fs[0] * inv, interp[1] * fs[1] * inv,
                       interp[2] * fs[2] * inv, interp[3] * fs[3] * inv);
    o[1] = make_float4(interp[4] * fs[4] * inv, interp[5] * fs[5] * inv,
                       interp[6] * fs[6] * inv, interp[7] * fs[7] * inv);
}

// ---------------- fallback (ws too small): direct fp32 strided path ----------------
__global__ __launch_bounds__(256) void wpf_plain(const float* __restrict__ pts,
                                                 const float* __restrict__ scales,
                                                 const float* __restrict__ p0,
                                                 const float* __restrict__ p1,
                                                 const float* __restrict__ p2,
                                                 const float* __restrict__ aabb,
                                                 float* __restrict__ out, int n) {
    const float offx[13] = {0.f, -1.f, -0.5f, 0.5f, 1.f, 0.f, 0.f, 0.f, 0.f, 0.5f, 0.5f, -0.5f, -0.5f};
    const float offy[13] = {0.f, 0.f, 0.f, 0.f, 0.f, -1.f, -0.5f, 0.5f, 1.f, 0.5f, -0.5f, 0.5f, -0.5f};
    int t = blockIdx.x * 256 + threadIdx.x;
    int pt = t >> 3;
    int cg_ = t & 7;
    if (pt >= n) return;
    float a00 = aabb[0], a01 = aabb[1], a02 = aabb[2];
    float a10 = aabb[3], a11 = aabb[4], a12 = aabb[5];
    float px = (pts[pt * 3 + 0] - a00) * (2.0f / (a10 - a00)) - 1.0f;
    float py = (pts[pt * 3 + 1] - a01) * (2.0f / (a11 - a01)) - 1.0f;
    float pz = (pts[pt * 3 + 2] - a02) * (2.0f / (a12 - a02)) - 1.0f;
    float scx = scales[pt * 3 + 0], scy = scales[pt * 3 + 1], scz = scales[pt * 3 + 2];
    float4 interp = make_float4(1.f, 1.f, 1.f, 1.f);
    for (int pair = 0; pair < 3; ++pair) {
        const float* plane = pair == 0 ? p0 : (pair == 1 ? p1 : p2);
        float bx = pair == 2 ? py : px;
        float by = pair == 0 ? py : pz;
        float sx = pair == 2 ? scy : scx;
        float sy = pair == 0 ? scy : scz;
        float4 featsum = make_float4(0.f, 0.f, 0.f, 0.f);
        for (int s = 0; s < 13; ++s) {
            float x = fminf(fmaxf((bx + sx * offx[s] + 1.0f) * 127.5f, 0.0f), 255.0f);
            float y = fminf(fmaxf((by + sy * offy[s] + 1.0f) * 127.5f, 0.0f), 255.0f);
            float x0f = floorf(x), y0f = floorf(y);
            float wx = x - x0f, wy = y - y0f;
            int x0 = (int)x0f, y0 = (int)y0f;
            int x1 = min(x0 + 1, RES - 1), y1 = min(y0 + 1, RES - 1);
            float w00 = (1.0f - wx) * (1.0f - wy), w10 = wx * (1.0f - wy);
            float w01 = (1.0f - wx) * wy, w11 = wx * wy;
            int c0 = cg_ << 2;
            for (int c = 0; c < 4; ++c) {
                const float* pl = plane + (size_t)(c0 + c) * (RES * RES);
                float f = pl[y0 * RES + x0] * w00 + pl[y0 * RES + x1] * w10 +
                          pl[y1 * RES + x0] * w01 + pl[y1 * RES + x1] * w11;
                (&featsum.x)[c] += f;
            }
        }
        const float inv13 = 1.0f / 13.0f;
        interp.x *= featsum.x * inv13;
        interp.y *= featsum.y * inv13;
        interp.z *= featsum.z * inv13;
        interp.w *= featsum.w * inv13;
    }
    reinterpret_cast<float4*>(out)[(size_t)pt * 8 + cg_] = interp;
}

extern "C" void kernel_launch(void* const* d_in, const int* in_sizes, int n_in,
                              void* d_out, int out_size, void* d_ws, size_t ws_size,
                              hipStream_t stream) {
    const float* pts    = (const float*)d_in[0];
    const float* scales = (const float*)d_in[2];
    const float* p0     = (const float*)d_in[3];
    const float* p1     = (const float*)d_in[4];
    const float* p2     = (const float*)d_in[5];
    const float* aabb   = (const float*)d_in[6];
    float* out = (float*)d_out;

    int n = in_sizes[0] / 3;
    int pt_blocks = (n + 255) / 256;

    // workspace layout
    size_t planes_hbytes = (size_t)3 * PLANE_ELEMS * sizeof(__half);  // 12 MB
    size_t ppk_bytes = (size_t)n * 8 * sizeof(float);                 // 16 MB
    size_t idx_bytes = (size_t)n * sizeof(int);                       // 2 MB
    size_t hist_bytes = (size_t)NBINS * sizeof(int);
    size_t need = planes_hbytes + ppk_bytes + idx_bytes + hist_bytes;

    if (ws_size >= need) {
        __half* planes_h = (__half*)d_ws;
        float*  ppk   = (float*)((char*)d_ws + planes_hbytes);
        int*    idx_s = (int*)((char*)ppk + ppk_bytes);
        int*    hist  = idx_s + n;

        hipMemsetAsync(hist, 0, hist_bytes, stream);
        pre_tq_hist<<<TQ_BLOCKS + pt_blocks, 256, 0, stream>>>(p0, p1, p2, planes_h,
                                                               pts, aabb, hist, n);
        scan_hist<<<1, 1024, 0, stream>>>(hist);
        scatter_pack<<<pt_blocks, 256, 0, stream>>>(pts, scales, aabb, hist,
                                                    ppk, idx_s, n);
        int main_blocks = (n * 4 + 255) / 256;
        int swizzle = (main_blocks % 8 == 0) ? 1 : 0;
        wpf_main4<<<main_blocks, 256, 0, stream>>>(ppk, idx_s, planes_h, out, n, swizzle);
    } else {
        int main_blocks = (n * 8 + 255) / 256;
        wpf_plain<<<main_blocks, 256, 0, stream>>>(pts, scales, p0, p1, p2, aabb, out, n);
    }
}

// Round 11
// 319.399 us; speedup vs baseline: 2.8362x; 1.0097x over previous
//
#include <hip/hip_runtime.h>
#include <hip/hip_fp16.h>

#define RES 256
#define FEAT 32
#define PLANE_ELEMS (FEAT * RES * RES)   // 2097152, fp16 plane = 4 MB
#define PLANE_BYTES (PLANE_ELEMS * 2)    // 4194304
#define NBINS 32768                      // 32^3 Morton bins
#define TQ_BLOCKS (3 * 256 * 4)          // transpose sub-grid of merged pre kernel

typedef unsigned u32x4 __attribute__((ext_vector_type(4)));

// ---------------- preprocessing ----------------
// LEDGER (do not retry): grid.sync() ~100us/sync (r7, VALUBusy 0.8%); per-block
// device __threadfence ticket ~600us (r9, VALUBusy 0.4%) — cross-XCD visibility
// ops at grid scale are catastrophically expensive on 8 non-coherent L2s.
// Dispatch boundaries (~20-30us each) are the CHEAP ordering primitive here.
// Sort removal: main 172->365us, FETCH 28MB->1.18GB (r8). Sort is mandatory.

__device__ inline unsigned spread3(unsigned v) {
    unsigned r = 0;
    r |= (v & 1u);
    r |= (v & 2u) << 2;
    r |= (v & 4u) << 4;
    r |= (v & 8u) << 6;
    r |= (v & 16u) << 8;
    return r;
}

// Merged: blocks [0,TQ_BLOCKS) transpose+quantize planes (C,H,W)fp32 -> (H,W,C)fp16
// via LDS tile; blocks [TQ_BLOCKS, ...) build Morton histogram (keys NOT stored;
// scatter recomputes them from pts with identical float math).
__global__ __launch_bounds__(256) void pre_tq_hist(const float* __restrict__ p0,
                                                   const float* __restrict__ p1,
                                                   const float* __restrict__ p2,
                                                   __half* __restrict__ outp,
                                                   const float* __restrict__ pts,
                                                   const float* __restrict__ aabb,
                                                   int* __restrict__ hist, int n) {
    int tid = threadIdx.x;
    if (blockIdx.x < TQ_BLOCKS) {
        __shared__ unsigned lds[64 * 17];            // [x][c2], pad 17: conflict-free
        int bid = blockIdx.x;
        int pl = bid >> 10;                          // /1024
        int rem = bid & 1023;
        int y = rem >> 2;
        int xbase = (rem & 3) * 64;
        const float* in = pl == 0 ? p0 : (pl == 1 ? p1 : p2);

        // phase 1: read along x (coalesced 256 B rows), pack channel pairs
        {
            int x = tid & 63;
            int c2b = (tid >> 6) * 4;                // 4 channel-pairs per thread
#pragma unroll
            for (int cc = 0; cc < 4; ++cc) {
                int c2 = c2b + cc;
                float f0 = in[(2 * c2) * (RES * RES) + y * RES + xbase + x];
                float f1 = in[(2 * c2 + 1) * (RES * RES) + y * RES + xbase + x];
                unsigned u = (unsigned)__half_as_ushort(__float2half(f0)) |
                             ((unsigned)__half_as_ushort(__float2half(f1)) << 16);
                lds[x * 17 + c2] = u;
            }
        }
        __syncthreads();

        // phase 2: write contiguous (x,c) order
        {
            unsigned* o32 = reinterpret_cast<unsigned*>(outp) + (size_t)pl * (PLANE_ELEMS / 2);
            int c2 = tid & 15;
            int xo = (tid >> 4) & 15;
#pragma unroll
            for (int xx = 0; xx < 4; ++xx) {
                int x = xx * 16 + xo;
                o32[(size_t)(y * 256 + xbase + x) * 16 + c2] = lds[x * 17 + c2];
            }
        }
    } else {
        int i = (blockIdx.x - TQ_BLOCKS) * 256 + tid;
        if (i >= n) return;
        float a00 = aabb[0], a01 = aabb[1], a02 = aabb[2];
        float a10 = aabb[3], a11 = aabb[4], a12 = aabb[5];
        float px = (pts[i * 3 + 0] - a00) * (2.0f / (a10 - a00)) - 1.0f;
        float py = (pts[i * 3 + 1] - a01) * (2.0f / (a11 - a01)) - 1.0f;
        float pz = (pts[i * 3 + 2] - a02) * (2.0f / (a12 - a02)) - 1.0f;
        unsigned ux = (unsigned)min(max((int)((px + 1.0f) * 16.0f), 0), 31);
        unsigned uy = (unsigned)min(max((int)((py + 1.0f) * 16.0f), 0), 31);
        unsigned uz = (unsigned)min(max((int)((pz + 1.0f) * 16.0f), 0), 31);
        int key = (int)(spread3(ux) | (spread3(uy) << 1) | (spread3(uz) << 2));
        atomicAdd(&hist[key], 1);
    }
}

__global__ __launch_bounds__(1024) void scan_hist(int* __restrict__ hist) {
    __shared__ int sums[1024];
    int t = threadIdx.x;
    int base = t * 32;
    int4 L[8];
    const int4* h4 = reinterpret_cast<const int4*>(hist + base);
#pragma unroll
    for (int i = 0; i < 8; ++i) L[i] = h4[i];
    int s = 0;
#pragma unroll
    for (int i = 0; i < 8; ++i) s += L[i].x + L[i].y + L[i].z + L[i].w;
    sums[t] = s;
    __syncthreads();
    for (int off = 1; off < 1024; off <<= 1) {
        int v = 0;
        if (t >= off) v = sums[t - off];
        __syncthreads();
        if (t >= off) sums[t] += v;
        __syncthreads();
    }
    int excl = (t == 0) ? 0 : sums[t - 1];
    int4* o4 = reinterpret_cast<int4*>(hist + base);
#pragma unroll
    for (int i = 0; i < 8; ++i) {
        int4 v;
        v.x = excl; excl += L[i].x;
        v.y = excl; excl += L[i].y;
        v.z = excl; excl += L[i].z;
        v.w = excl; excl += L[i].w;
        o4[i] = v;
    }
}

// Scatter sorted, pre-transformed records: [cx,cy,cz,0, hx,hy,hz,0] in pixel units.
// cx = (pxn+1)*127.5 ; hx = sx*63.75. Key recomputed from pts (identical float
// math to pre_tq_hist -> identical key; drops the 4 MB keys[] round-trip).
__global__ __launch_bounds__(256) void scatter_pack(const float* __restrict__ pts,
                                                    const float* __restrict__ scales,
                                                    const float* __restrict__ aabb,
                                                    int* __restrict__ hist,
                                                    float* __restrict__ ppk,
                                                    int* __restrict__ idx_s, int n) {
    int i = blockIdx.x * 256 + threadIdx.x;
    if (i >= n) return;
    float a00 = aabb[0], a01 = aabb[1], a02 = aabb[2];
    float a10 = aabb[3], a11 = aabb[4], a12 = aabb[5];
    float px = (pts[i * 3 + 0] - a00) * (2.0f / (a10 - a00)) - 1.0f;
    float py = (pts[i * 3 + 1] - a01) * (2.0f / (a11 - a01)) - 1.0f;
    float pz = (pts[i * 3 + 2] - a02) * (2.0f / (a12 - a02)) - 1.0f;
    unsigned ux = (unsigned)min(max((int)((px + 1.0f) * 16.0f), 0), 31);
    unsigned uy = (unsigned)min(max((int)((py + 1.0f) * 16.0f), 0), 31);
    unsigned uz = (unsigned)min(max((int)((pz + 1.0f) * 16.0f), 0), 31);
    int key = (int)(spread3(ux) | (spread3(uy) << 1) | (spread3(uz) << 2));
    int pos = atomicAdd(&hist[key], 1);
    float4* o = reinterpret_cast<float4*>(ppk) + (size_t)pos * 2;
    o[0] = make_float4((px + 1.0f) * 127.5f, (py + 1.0f) * 127.5f, (pz + 1.0f) * 127.5f, 0.0f);
    o[1] = make_float4(scales[i * 3 + 0] * 63.75f, scales[i * 3 + 1] * 63.75f,
                       scales[i * 3 + 2] * 63.75f, 0.0f);
    idx_s[pos] = i;
}

// ---------------- main kernel ----------------

// Guaranteed convert+FMA fusion: acc(f32) += f16(lo/hi of dword) * w(f32).
#define MIX2(f0, f1, d, w)                                                              \
    asm("v_fma_mix_f32 %0, %1, %2, %0 op_sel_hi:[1,0,0]" : "+v"(f0) : "v"(d), "v"(w)); \
    asm("v_fma_mix_f32 %0, %1, %2, %0 op_sel:[1,0,0] op_sel_hi:[1,0,0]" : "+v"(f1) : "v"(d), "v"(w))

__device__ __forceinline__ void mix8(float* fs, u32x4 v, float w) {
    MIX2(fs[0], fs[1], v[0], w);
    MIX2(fs[2], fs[3], v[1], w);
    MIX2(fs[4], fs[5], v[2], w);
    MIX2(fs[6], fs[7], v[3], w);
}

// 4 lanes per point, 8 channels per lane. One corner texel (64 B) = ONE wave load.
// Flat 39-sample pipeline across all 3 planes — now 3-DEEP: four pinned buffer
// sets X/Y/Z/W rotate mod 4; steady state ISSUE(s+3); vmcnt(12); CONSUME(s).
// 12 loads stay in flight per wave (was 8) to push TA/L1 saturation: measured
// floor is ~1 line-touch/cycle/CU (r1 calibration: 164M touches -> 266us
// predicted, 270 measured); 4-lane = 82M touches -> 133us floor, r6-r10 at 172.
// Consume order and arithmetic identical to r6 -> absmax bit-identical.
// (Sorted input REQUIRED: r8 measured unsorted = 1.18 GB fetch, 365 us.)
__global__ __launch_bounds__(256) void wpf_main4(const float* __restrict__ ppk,
                                                 const int* __restrict__ idx_s,
                                                 const __half* __restrict__ planes, // 3 concat
                                                 float* __restrict__ out, int n, int swizzle) {
    int b = blockIdx.x;
    if (swizzle) {
        int nb = gridDim.x;
        int chunk = nb >> 3;
        b = (b & 7) * chunk + (b >> 3);
    }
    int t = b * 256 + threadIdx.x;
    int pt = t >> 2;
    int cg_ = t & 3;
    if (pt >= n) return;

    float4 a  = reinterpret_cast<const float4*>(ppk)[(size_t)pt * 2];
    float4 hh = reinterpret_cast<const float4*>(ppk)[(size_t)pt * 2 + 1];
    int chan = cg_ * 16;                 // byte offset of this lane's 8 channels

    const int SI[13] = {2, 0, 1, 3, 4, 2, 2, 2, 2, 3, 3, 1, 1};
    const int SJ[13] = {2, 2, 2, 2, 2, 0, 1, 3, 4, 3, 1, 3, 1};

    float wx[2][5], wy[2][5];
    int   cA[2][5], rA[2][5];
    float fs[8] = {0, 0, 0, 0, 0, 0, 0, 0};
    float interp[8];
    u32x4 X0, X1, X2, X3, Y0, Y1, Y2, Y3, Z0, Z1, Z2, Z3, W0, W1, W2, W3;

#define SETUP(SET, CX, CY, HX, HY, POFF)                 \
    _Pragma("unroll")                                    \
    for (int k = 0; k < 5; ++k) {                        \
        float x_ = fmaf((float)(k - 2), (HX), (CX));     \
        int xi_ = (int)x_;              /* trunc==floor, x>0 */ \
        wx[SET][k] = x_ - (float)xi_;                    \
        cA[SET][k] = xi_ * 64 + chan;                    \
        float y_ = fmaf((float)(k - 2), (HY), (CY));     \
        int yi_ = (int)y_;                               \
        wy[SET][k] = y_ - (float)yi_;                    \
        rA[SET][k] = yi_ * (RES * 64) + (POFF);          \
    }

#define ISSUE(d0, d1, d2, d3, SET, M)                                                     \
    {                                                                                     \
        unsigned vo0_ = (unsigned)(rA[SET][SJ[M]] + cA[SET][SI[M]]);                      \
        unsigned vo1_ = vo0_ + 16384u;                                                    \
        asm volatile("global_load_dwordx4 %0, %1, %2"           : "=v"(d0) : "v"(vo0_), "s"(planes)); \
        asm volatile("global_load_dwordx4 %0, %1, %2 offset:64" : "=v"(d1) : "v"(vo0_), "s"(planes)); \
        asm volatile("global_load_dwordx4 %0, %1, %2"           : "=v"(d2) : "v"(vo1_), "s"(planes)); \
        asm volatile("global_load_dwordx4 %0, %1, %2 offset:64" : "=v"(d3) : "v"(vo1_), "s"(planes)); \
    }
#define WAIT12(b0, b1, b2, b3) \
    asm volatile("s_waitcnt vmcnt(12)" : "+v"(b0), "+v"(b1), "+v"(b2), "+v"(b3))
#define WAIT8(b0, b1, b2, b3) \
    asm volatile("s_waitcnt vmcnt(8)" : "+v"(b0), "+v"(b1), "+v"(b2), "+v"(b3))
#define WAIT4(b0, b1, b2, b3) \
    asm volatile("s_waitcnt vmcnt(4)" : "+v"(b0), "+v"(b1), "+v"(b2), "+v"(b3))
#define WAITZ(b0, b1, b2, b3) \
    asm volatile("s_waitcnt vmcnt(0)" : "+v"(b0), "+v"(b1), "+v"(b2), "+v"(b3))
#define CONSUME(SET, M, b0, b1, b2, b3)                  \
    {                                                    \
        float wxi = wx[SET][SI[M]], wyj = wy[SET][SJ[M]];\
        float wxc = 1.0f - wxi, wyc = 1.0f - wyj;        \
        mix8(fs, b0, wxc * wyc);                         \
        mix8(fs, b1, wxi * wyc);                         \
        mix8(fs, b2, wxc * wyj);                         \
        mix8(fs, b3, wxi * wyj);                         \
    }
// steady state: issue global sample CS+3 (slot set ISET), wait until <=12
// outstanding (sample CS's 4 loads done; CS+1..CS+3 in flight), consume CS.
#define STEP(CS, CSET, ISET, C0, C1, C2, C3, N0, N1, N2, N3) \
    ISSUE(N0, N1, N2, N3, ISET, ((CS) + 3) % 13);            \
    WAIT12(C0, C1, C2, C3);                                  \
    CONSUME(CSET, (CS) % 13, C0, C1, C2, C3);

        SETUP(0, a.x, a.y, hh.x, hh.y, 0)                 // plane 0
        ISSUE(X0, X1, X2, X3, 0, 0);
        ISSUE(Y0, Y1, Y2, Y3, 0, 1);
        ISSUE(Z0, Z1, Z2, Z3, 0, 2);
        STEP(0,  0, 0, X0, X1, X2, X3, W0, W1, W2, W3)    // issue s3
        STEP(1,  0, 0, Y0, Y1, Y2, Y3, X0, X1, X2, X3)
        STEP(2,  0, 0, Z0, Z1, Z2, Z3, Y0, Y1, Y2, Y3)
        STEP(3,  0, 0, W0, W1, W2, W3, Z0, Z1, Z2, Z3)
        STEP(4,  0, 0, X0, X1, X2, X3, W0, W1, W2, W3)
        STEP(5,  0, 0, Y0, Y1, Y2, Y3, X0, X1, X2, X3)
        STEP(6,  0, 0, Z0, Z1, Z2, Z3, Y0, Y1, Y2, Y3)
        STEP(7,  0, 0, W0, W1, W2, W3, Z0, Z1, Z2, Z3)
        STEP(8,  0, 0, X0, X1, X2, X3, W0, W1, W2, W3)
        STEP(9,  0, 0, Y0, Y1, Y2, Y3, X0, X1, X2, X3)    // issues s12 (last p0)
        SETUP(1, a.x, a.z, hh.x, hh.z, PLANE_BYTES)       // plane 1 slots, early
        STEP(10, 0, 1, Z0, Z1, Z2, Z3, Y0, Y1, Y2, Y3)    // issues s13 = p1 m0
        STEP(11, 0, 1, W0, W1, W2, W3, Z0, Z1, Z2, Z3)    // issues s14
        STEP(12, 0, 1, X0, X1, X2, X3, W0, W1, W2, W3)    // consumes p0 m12; issues s15
#pragma unroll
        for (int c = 0; c < 8; ++c) { interp[c] = fs[c]; fs[c] = 0.0f; }
        STEP(13, 1, 1, Y0, Y1, Y2, Y3, X0, X1, X2, X3)
        STEP(14, 1, 1, Z0, Z1, Z2, Z3, Y0, Y1, Y2, Y3)
        STEP(15, 1, 1, W0, W1, W2, W3, Z0, Z1, Z2, Z3)
        STEP(16, 1, 1, X0, X1, X2, X3, W0, W1, W2, W3)
        STEP(17, 1, 1, Y0, Y1, Y2, Y3, X0, X1, X2, X3)
        STEP(18, 1, 1, Z0, Z1, Z2, Z3, Y0, Y1, Y2, Y3)
        STEP(19, 1, 1, W0, W1, W2, W3, Z0, Z1, Z2, Z3)
        STEP(20, 1, 1, X0, X1, X2, X3, W0, W1, W2, W3)
        STEP(21, 1, 1, Y0, Y1, Y2, Y3, X0, X1, X2, X3)
        STEP(22, 1, 1, Z0, Z1, Z2, Z3, Y0, Y1, Y2, Y3)    // issues s25 (last p1)
        SETUP(0, a.y, a.z, hh.y, hh.z, 2 * PLANE_BYTES)   // plane 2 slots, early
        STEP(23, 1, 0, W0, W1, W2, W3, Z0, Z1, Z2, Z3)    // issues s26 = p2 m0
        STEP(24, 1, 0, X0, X1, X2, X3, W0, W1, W2, W3)    // issues s27
        STEP(25, 1, 0, Y0, Y1, Y2, Y3, X0, X1, X2, X3)    // consumes p1 m12; issues s28
#pragma unroll
        for (int c = 0; c < 8; ++c) { interp[c] *= fs[c]; fs[c] = 0.0f; }
        STEP(26, 0, 0, Z0, Z1, Z2, Z3, Y0, Y1, Y2, Y3)
        STEP(27, 0, 0, W0, W1, W2, W3, Z0, Z1, Z2, Z3)
        STEP(28, 0, 0, X0, X1, X2, X3, W0, W1, W2, W3)
        STEP(29, 0, 0, Y0, Y1, Y2, Y3, X0, X1, X2, X3)
        STEP(30, 0, 0, Z0, Z1, Z2, Z3, Y0, Y1, Y2, Y3)
        STEP(31, 0, 0, W0, W1, W2, W3, Z0, Z1, Z2, Z3)
        STEP(32, 0, 0, X0, X1, X2, X3, W0, W1, W2, W3)
        STEP(33, 0, 0, Y0, Y1, Y2, Y3, X0, X1, X2, X3)
        STEP(34, 0, 0, Z0, Z1, Z2, Z3, Y0, Y1, Y2, Y3)
        STEP(35, 0, 0, W0, W1, W2, W3, Z0, Z1, Z2, Z3)    // consumes s35; issues s38
        WAIT8(X0, X1, X2, X3);                            // s36 ready, s37/s38 in flight
        CONSUME(0, 10, X0, X1, X2, X3);
        WAIT4(Y0, Y1, Y2, Y3);                            // s37 ready
        CONSUME(0, 11, Y0, Y1, Y2, Y3);
        WAITZ(Z0, Z1, Z2, Z3);                            // s38 ready
        CONSUME(0, 12, Z0, Z1, Z2, Z3);

#undef SETUP
#undef ISSUE
#undef WAIT12
#undef WAIT8
#undef WAIT4
#undef WAITZ
#undef CONSUME
#undef STEP

    const float inv = 1.0f / 2197.0f;    // (1/13)^3 folded into epilogue
    int oi = idx_s[pt];
    float4* o = reinterpret_cast<float4*>(out + (size_t)oi * 32 + cg_ * 8);
    o[0] = make_float4(interp[0] * fs[0] * inv, interp[1] * fs[1] * inv,
                       interp[2] * fs[2] * inv, interp[3] * fs[3] * inv);
    o[1] = make_float4(interp[4] * fs[4] * inv, interp[5] * fs[5] * inv,
                       interp[6] * fs[6] * inv, interp[7] * fs[7] * inv);
}

// ---------------- fallback (ws too small): direct fp32 strided path ----------------
__global__ __launch_bounds__(256) void wpf_plain(const float* __restrict__ pts,
                                                 const float* __restrict__ scales,
                                                 const float* __restrict__ p0,
                                                 const float* __restrict__ p1,
                                                 const float* __restrict__ p2,
                                                 const float* __restrict__ aabb,
                                                 float* __restrict__ out, int n) {
    const float offx[13] = {0.f, -1.f, -0.5f, 0.5f, 1.f, 0.f, 0.f, 0.f, 0.f, 0.5f, 0.5f, -0.5f, -0.5f};
    const float offy[13] = {0.f, 0.f, 0.f, 0.f, 0.f, -1.f, -0.5f, 0.5f, 1.f, 0.5f, -0.5f, 0.5f, -0.5f};
    int t = blockIdx.x * 256 + threadIdx.x;
    int pt = t >> 3;
    int cg_ = t & 7;
    if (pt >= n) return;
    float a00 = aabb[0], a01 = aabb[1], a02 = aabb[2];
    float a10 = aabb[3], a11 = aabb[4], a12 = aabb[5];
    float px = (pts[pt * 3 + 0] - a00) * (2.0f / (a10 - a00)) - 1.0f;
    float py = (pts[pt * 3 + 1] - a01) * (2.0f / (a11 - a01)) - 1.0f;
    float pz = (pts[pt * 3 + 2] - a02) * (2.0f / (a12 - a02)) - 1.0f;
    float scx = scales[pt * 3 + 0], scy = scales[pt * 3 + 1], scz = scales[pt * 3 + 2];
    float4 interp = make_float4(1.f, 1.f, 1.f, 1.f);
    for (int pair = 0; pair < 3; ++pair) {
        const float* plane = pair == 0 ? p0 : (pair == 1 ? p1 : p2);
        float bx = pair == 2 ? py : px;
        float by = pair == 0 ? py : pz;
        float sx = pair == 2 ? scy : scx;
        float sy = pair == 0 ? scy : scz;
        float4 featsum = make_float4(0.f, 0.f, 0.f, 0.f);
        for (int s = 0; s < 13; ++s) {
            float x = fminf(fmaxf((bx + sx * offx[s] + 1.0f) * 127.5f, 0.0f), 255.0f);
            float y = fminf(fmaxf((by + sy * offy[s] + 1.0f) * 127.5f, 0.0f), 255.0f);
            float x0f = floorf(x), y0f = floorf(y);
            float wx = x - x0f, wy = y - y0f;
            int x0 = (int)x0f, y0 = (int)y0f;
            int x1 = min(x0 + 1, RES - 1), y1 = min(y0 + 1, RES - 1);
            float w00 = (1.0f - wx) * (1.0f - wy), w10 = wx * (1.0f - wy);
            float w01 = (1.0f - wx) * wy, w11 = wx * wy;
            int c0 = cg_ << 2;
            for (int c = 0; c < 4; ++c) {
                const float* pl = plane + (size_t)(c0 + c) * (RES * RES);
                float f = pl[y0 * RES + x0] * w00 + pl[y0 * RES + x1] * w10 +
                          pl[y1 * RES + x0] * w01 + pl[y1 * RES + x1] * w11;
                (&featsum.x)[c] += f;
            }
        }
        const float inv13 = 1.0f / 13.0f;
        interp.x *= featsum.x * inv13;
        interp.y *= featsum.y * inv13;
        interp.z *= featsum.z * inv13;
        interp.w *= featsum.w * inv13;
    }
    reinterpret_cast<float4*>(out)[(size_t)pt * 8 + cg_] = interp;
}

extern "C" void kernel_launch(void* const* d_in, const int* in_sizes, int n_in,
                              void* d_out, int out_size, void* d_ws, size_t ws_size,
                              hipStream_t stream) {
    const float* pts    = (const float*)d_in[0];
    const float* scales = (const float*)d_in[2];
    const float* p0     = (const float*)d_in[3];
    const float* p1     = (const float*)d_in[4];
    const float* p2     = (const float*)d_in[5];
    const float* aabb   = (const float*)d_in[6];
    float* out = (float*)d_out;

    int n = in_sizes[0] / 3;
    int pt_blocks = (n + 255) / 256;

    // workspace layout
    size_t planes_hbytes = (size_t)3 * PLANE_ELEMS * sizeof(__half);  // 12 MB
    size_t ppk_bytes = (size_t)n * 8 * sizeof(float);                 // 16 MB
    size_t idx_bytes = (size_t)n * sizeof(int);                       // 2 MB
    size_t hist_bytes = (size_t)NBINS * sizeof(int);
    size_t need = planes_hbytes + ppk_bytes + idx_bytes + hist_bytes;

    if (ws_size >= need) {
        __half* planes_h = (__half*)d_ws;
        float*  ppk   = (float*)((char*)d_ws + planes_hbytes);
        int*    idx_s = (int*)((char*)ppk + ppk_bytes);
        int*    hist  = idx_s + n;

        hipMemsetAsync(hist, 0, hist_bytes, stream);
        pre_tq_hist<<<TQ_BLOCKS + pt_blocks, 256, 0, stream>>>(p0, p1, p2, planes_h,
                                                               pts, aabb, hist, n);
        scan_hist<<<1, 1024, 0, stream>>>(hist);
        scatter_pack<<<pt_blocks, 256, 0, stream>>>(pts, scales, aabb, hist,
                                                    ppk, idx_s, n);
        int main_blocks = (n * 4 + 255) / 256;
        int swizzle = (main_blocks % 8 == 0) ? 1 : 0;
        wpf_main4<<<main_blocks, 256, 0, stream>>>(ppk, idx_s, planes_h, out, n, swizzle);
    } else {
        int main_blocks = (n * 8 + 255) / 256;
        wpf_plain<<<main_blocks, 256, 0, stream>>>(pts, scales, p0, p1, p2, aabb, out, n);
    }
}